// Round 3
// baseline (273.277 us; speedup 1.0000x reference)
//
#include <hip/hip_runtime.h>
#include <stdint.h>

#define BATCH 8
#define NCH 256
#define BCH 128
#define KFR 32000
#define TOUT 256008
#define KT 32
#define NTPB 8
#define CHUNK (KT * NTPB)        // 256 frames per block
#define NCHUNK (KFR / CHUNK)     // 125

typedef __attribute__((ext_vector_type(8))) short bf16x8;
typedef __attribute__((ext_vector_type(4))) float f32x4;

__device__ __forceinline__ unsigned short f32_to_bf16(float f) {
    unsigned int u = __builtin_bit_cast(unsigned int, f);
    u += 0x7FFFu + ((u >> 16) & 1u);
    return (unsigned short)(u >> 16);
}
__device__ __forceinline__ float bf16_to_f32(unsigned short h) {
    unsigned int u = ((unsigned int)h) << 16;
    return __builtin_bit_cast(float, u);
}
__device__ __forceinline__ unsigned int pack2(float a, float b) {
    return (unsigned int)f32_to_bf16(a) | ((unsigned int)f32_to_bf16(b) << 16);
}

__global__ void convert_weights(const float* __restrict__ Wm,
                                const float* __restrict__ Wb,
                                unsigned short* __restrict__ wbf) {
    int i = blockIdx.x * 256 + threadIdx.x;
    if (i < NCH * BCH) wbf[i] = f32_to_bf16(Wm[i]);
    if (i < 16 * NCH)  wbf[NCH * BCH + i] = f32_to_bf16(Wb[i]);
}

// LDS (units of 4B words):
//   estd [32 f][68 w]  : est^T bf16, XOR-swizzled at 16B granularity
//   xtd  [32 f][132 w] : m/x bf16, XOR-swizzled at 16B granularity
//   locout[2056] f32   : whole-chunk overlap-add accumulator
#define ESTT_W 68
#define XT_W 132
#define ESTT_WORDS (KT * ESTT_W)     // 2176
#define XT_WORDS (KT * XT_W)         // 4224
#define LOC_FLOATS (8 * CHUNK + 8)   // 2056

__launch_bounds__(256, 4)
__global__ void fused_decoder(const float* __restrict__ mix,
                              const float* __restrict__ est,
                              const unsigned short* __restrict__ wbf,
                              float* __restrict__ out) {
    __shared__ __align__(16) unsigned int smem[ESTT_WORDS + XT_WORDS + LOC_FLOATS];
    unsigned int* estd = smem;
    unsigned int* xtd  = smem + ESTT_WORDS;
    unsigned short* estT = reinterpret_cast<unsigned short*>(estd);
    unsigned short* xt   = reinterpret_cast<unsigned short*>(xtd);
    float* locout = reinterpret_cast<float*>(smem + ESTT_WORDS + XT_WORDS);

    const int tid = threadIdx.x;
    const int lane = tid & 63;
    const int wv = tid >> 6;
    const int l15 = lane & 15;
    const int lq = lane >> 4;
    const int f4 = tid & 7;          // staging frame-quad
    const int rbase = tid >> 3;      // staging row base

    const int bid = blockIdx.x;
    const int g = bid / NCHUNK;
    const int c = bid % NCHUNK;

    const float* eg0 = est + ((size_t)g * BCH) * KFR + c * CHUNK;
    const float* mg0 = mix + ((size_t)g * NCH) * KFR + c * CHUNK;

    // zero the chunk accumulator (2056 = 514 float4)
    for (int s = tid; s < LOC_FLOATS / 4; s += 256) {
        float4 z = {0.f, 0.f, 0.f, 0.f};
        *reinterpret_cast<float4*>(locout + 4 * s) = z;
    }

    // prologue: issue est[0] loads
    float4 er[2][2];
#pragma unroll
    for (int it = 0; it < 2; ++it) {
        int bp = it * 32 + rbase;
        er[it][0] = *reinterpret_cast<const float4*>(eg0 + (size_t)(2 * bp) * KFR + 4 * f4);
        er[it][1] = *reinterpret_cast<const float4*>(eg0 + (size_t)(2 * bp + 1) * KFR + 4 * f4);
    }

    for (int t = 0; t < NTPB; ++t) {
        const float* mg = mg0 + t * KT;
        const float* egn = eg0 + (t + 1 < NTPB ? (t + 1) * KT : t * KT);

        // ---- phase A: est regs -> LDS (swizzled); issue est[t+1] + mix[t] ----
        {
            int msk = (f4 >> 1) & 3;
#pragma unroll
            for (int it = 0; it < 2; ++it) {
                int bp = it * 32 + rbase;
                int base = (((bp >> 2) ^ msk) << 2) + (bp & 3);
#pragma unroll
                for (int i = 0; i < 4; ++i) {
                    unsigned int p = pack2((&er[it][0].x)[i], (&er[it][1].x)[i]);
                    estd[(4 * f4 + i) * ESTT_W + base] = p;
                }
            }
        }
#pragma unroll
        for (int it = 0; it < 2; ++it) {       // prefetch next tile's est
            int bp = it * 32 + rbase;
            er[it][0] = *reinterpret_cast<const float4*>(egn + (size_t)(2 * bp) * KFR + 4 * f4);
            er[it][1] = *reinterpret_cast<const float4*>(egn + (size_t)(2 * bp + 1) * KFR + 4 * f4);
        }
        float4 mr[4][2];                       // this tile's mix, in flight until phase C
#pragma unroll
        for (int it = 0; it < 4; ++it) {
            int np = it * 32 + rbase;
            mr[it][0] = *reinterpret_cast<const float4*>(mg + (size_t)(2 * np) * KFR + 4 * f4);
            mr[it][1] = *reinterpret_cast<const float4*>(mg + (size_t)(2 * np + 1) * KFR + 4 * f4);
        }
        __syncthreads();

        // ---- phase B: GEMM1 m[n][f] = W[n][b] est[b][f]; m -> xt (bf16, swizzled) ----
        f32x4 acc[4][2];
#pragma unroll
        for (int nt = 0; nt < 4; ++nt)
#pragma unroll
            for (int ft = 0; ft < 2; ++ft) {
                f32x4 z = {0.f, 0.f, 0.f, 0.f};
                acc[nt][ft] = z;
            }
#pragma unroll
        for (int nt = 0; nt < 4; ++nt) {
            int n = 64 * wv + 16 * nt + l15;
            bf16x8 wf[4];
#pragma unroll
            for (int ks = 0; ks < 4; ++ks)
                wf[ks] = *reinterpret_cast<const bf16x8*>(wbf + n * BCH + 32 * ks + 8 * lq);
#pragma unroll
            for (int ft = 0; ft < 2; ++ft) {
                int f = 16 * ft + l15;
                int msk = (2 * ft + (l15 >> 3)) & 3;
#pragma unroll
                for (int ks = 0; ks < 4; ++ks) {
                    bf16x8 b = *reinterpret_cast<const bf16x8*>(
                        estT + f * (2 * ESTT_W) + 8 * ((4 * ks + lq) ^ msk));
                    acc[nt][ft] = __builtin_amdgcn_mfma_f32_16x16x32_bf16(wf[ks], b, acc[nt][ft], 0, 0, 0);
                }
            }
        }
#pragma unroll
        for (int nt = 0; nt < 4; ++nt)
#pragma unroll
            for (int ft = 0; ft < 2; ++ft) {
                int f = 16 * ft + l15;
                int msk = (2 * ft + (l15 >> 3)) & 3;
                int v = 8 * wv + 2 * nt + (lq >> 1);
                int word = f * XT_W + (((v ^ msk) << 2)) + 2 * (lq & 1);
                uint2 u;
                u.x = pack2(acc[nt][ft][0], acc[nt][ft][1]);
                u.y = pack2(acc[nt][ft][2], acc[nt][ft][3]);
                *reinterpret_cast<uint2*>(xtd + word) = u;
            }
        __syncthreads();

        // ---- phase C: x = mix * relu(m), in-place on xt (swizzled b32 RMW) ----
        {
            int msk = (f4 >> 1) & 3;
#pragma unroll
            for (int it = 0; it < 4; ++it) {
                int np = it * 32 + rbase;
                int base = (((np >> 2) ^ msk) << 2) + (np & 3);
#pragma unroll
                for (int i = 0; i < 4; ++i) {
                    int idx = (4 * f4 + i) * XT_W + base;
                    unsigned int p = xtd[idx];
                    float m0 = bf16_to_f32((unsigned short)(p & 0xFFFFu));
                    float m1 = bf16_to_f32((unsigned short)(p >> 16));
                    float x0 = (m0 > 0.f) ? (&mr[it][0].x)[i] * m0 : 0.f;
                    float x1 = (m1 > 0.f) ? (&mr[it][1].x)[i] * m1 : 0.f;
                    xtd[idx] = pack2(x0, x1);
                }
            }
        }
        __syncthreads();

        // ---- phase D: GEMM2 y[l][f] = Wb[l][n] x[n][f]; overlap-add into locout ----
        f32x4 acc2 = {0.f, 0.f, 0.f, 0.f};
        if (wv < 2) {
            int f = 16 * wv + l15;
            int msk = (2 * wv + (l15 >> 3)) & 3;
#pragma unroll
            for (int ks = 0; ks < 8; ++ks) {
                bf16x8 a = *reinterpret_cast<const bf16x8*>(
                    wbf + NCH * BCH + l15 * NCH + 32 * ks + 8 * lq);
                bf16x8 b = *reinterpret_cast<const bf16x8*>(
                    xt + f * (2 * XT_W) + 8 * ((4 * ks + lq) ^ msk));
                acc2 = __builtin_amdgcn_mfma_f32_16x16x32_bf16(a, b, acc2, 0, 0, 0);
            }
        }
        if (wv < 2 && lq < 2) {          // pass 1: louts 0..7, disjoint addresses
            int f = 16 * wv + l15;
            int base = 256 * t + 8 * f + 4 * lq;
#pragma unroll
            for (int r = 0; r < 4; ++r) locout[base + r] += acc2[r];
        }
        __syncthreads();
        if (wv < 2 && lq >= 2) {         // pass 2: louts 8..15, disjoint addresses
            int f = 16 * wv + l15;
            int base = 256 * t + 8 * f + 4 * lq;
#pragma unroll
            for (int r = 0; r < 4; ++r) locout[base + r] += acc2[r];
        }
        // no barrier needed: next conflicting LDS access is after phase-A barrier
    }
    __syncthreads();

    // ---- final store: whole chunk, plain float4 interior, atomic 8-float edges ----
    {
        float* og = out + (size_t)g * TOUT + (size_t)(8 * CHUNK) * c;
        for (int s = tid; s < LOC_FLOATS / 4; s += 256) {
            float4 v = *reinterpret_cast<const float4*>(locout + 4 * s);
            if (s >= 2 && s < (LOC_FLOATS / 4 - 2)) {
                *reinterpret_cast<float4*>(og + 4 * s) = v;
            } else {
#pragma unroll
                for (int r = 0; r < 4; ++r) atomicAdd(og + 4 * s + r, (&v.x)[r]);
            }
        }
    }
}

extern "C" void kernel_launch(void* const* d_in, const int* in_sizes, int n_in,
                              void* d_out, int out_size, void* d_ws, size_t ws_size,
                              hipStream_t stream) {
    const float* mix = (const float*)d_in[0];   // [8][256][32000]
    const float* est = (const float*)d_in[1];   // [8][128][32000]
    const float* Wm  = (const float*)d_in[2];   // [256][128]
    const float* Wb  = (const float*)d_in[3];   // [16][256]
    unsigned short* wbf = (unsigned short*)d_ws;

    hipMemsetAsync(d_out, 0, (size_t)out_size * sizeof(float), stream);
    convert_weights<<<128, 256, 0, stream>>>(Wm, Wb, wbf);
    fused_decoder<<<BATCH * NCHUNK, 256, 0, stream>>>(mix, est, wbf, (float*)d_out);
}